// Round 13
// baseline (501.360 us; speedup 1.0000x reference)
//
#include <hip/hip_runtime.h>
#include <stdint.h>

// RecursiveLSTM: B=1024 seqs, T=96, H=50, num_pred=12. Wave-per-sequence.
// ROUND-13: SINGLE-pass, DEEP 7-slot b128 staging rotation. r8/r11/r12
// post-mortem: busy/step constant ~650, idle/step ~30 cyc x (#blocking
// s_waitcnt) in all three -- the cost is wait-restart overhead at ~128-cyc
// read-ahead ~= 120-cyc LDS latency, not per-pass latency (else 2/3-way
// interleave would have absorbed it). Fix: reads run 192-224 cyc ahead of
// consumption (7 slots, 13 reads/step, reissue-after-consume), so every
// group wait finds data landed. Single pass frees the registers the deep
// rotation needs (2-pass + 7 slots does not fit with 208 weight regs).
// Weights (bias,W_ih fused as pair0) in v48..255, loaded ONCE (r12).
// Exposed serial cost kept honest: tail ~150 + hn->read turnaround ~60.
//
// Reg map: v0-27 staging S0..S6 | v28-35 acc pairs i,f,g,o | v36 c | v37 hn
// v38 lds base | v39 hn-write addr | v40 xa | v41 wfc | v42 x-tmp
// v44-45 FC tmp | v48-255 weights (i:48-99 f:100-151 g:152-203 o:204-255)

#define HSZ 50
#define TLEN 96

#define GRP(WT,A0,A1,A2,A3,IL,IH,FL,FH,GL,GH,OL,OH,BL,BH,POST) \
    "s_waitcnt lgkmcnt(" WT ")\n\t" \
    "v_pk_fma_f32 v[" A0 "], v[" IL "], v[" BL "], v[" A0 "]\n\t" \
    "v_pk_fma_f32 v[" A1 "], v[" FL "], v[" BL "], v[" A1 "]\n\t" \
    "v_pk_fma_f32 v[" A2 "], v[" GL "], v[" BL "], v[" A2 "]\n\t" \
    "v_pk_fma_f32 v[" A3 "], v[" OL "], v[" BL "], v[" A3 "]\n\t" \
    "v_pk_fma_f32 v[" A0 "], v[" IH "], v[" BH "], v[" A0 "]\n\t" \
    "v_pk_fma_f32 v[" A1 "], v[" FH "], v[" BH "], v[" A1 "]\n\t" \
    "v_pk_fma_f32 v[" A2 "], v[" GH "], v[" BH "], v[" A2 "]\n\t" \
    "v_pk_fma_f32 v[" A3 "], v[" OH "], v[" BH "], v[" A3 "]\n\t" \
    POST
#define GRPM(WT,A0,A1,A2,A3,IL,IH,FL,FH,GL,GH,OL,OH,BL,BH,POST) \
    "s_waitcnt lgkmcnt(" WT ")\n\t" \
    "v_pk_mul_f32 v[" A0 "], v[" IL "], v[" BL "]\n\t" \
    "v_pk_mul_f32 v[" A1 "], v[" FL "], v[" BL "]\n\t" \
    "v_pk_mul_f32 v[" A2 "], v[" GL "], v[" BL "]\n\t" \
    "v_pk_mul_f32 v[" A3 "], v[" OL "], v[" BL "]\n\t" \
    "v_pk_fma_f32 v[" A0 "], v[" IH "], v[" BH "], v[" A0 "]\n\t" \
    "v_pk_fma_f32 v[" A1 "], v[" FH "], v[" BH "], v[" A1 "]\n\t" \
    "v_pk_fma_f32 v[" A2 "], v[" GH "], v[" BH "], v[" A2 "]\n\t" \
    "v_pk_fma_f32 v[" A3 "], v[" OH "], v[" BH "], v[" A3 "]\n\t" \
    POST
#define GRPX(...)  GRP(__VA_ARGS__)
#define GRPMX(...) GRPM(__VA_ARGS__)

#define ACC "28:29","30:31","32:33","34:35"
#define W0  "48:49","50:51","100:101","102:103","152:153","154:155","204:205","206:207"
#define W1  "52:53","54:55","104:105","106:107","156:157","158:159","208:209","210:211"
#define W2  "56:57","58:59","108:109","110:111","160:161","162:163","212:213","214:215"
#define W3  "60:61","62:63","112:113","114:115","164:165","166:167","216:217","218:219"
#define W4  "64:65","66:67","116:117","118:119","168:169","170:171","220:221","222:223"
#define W5  "68:69","70:71","120:121","122:123","172:173","174:175","224:225","226:227"
#define W6  "72:73","74:75","124:125","126:127","176:177","178:179","228:229","230:231"
#define W7  "76:77","78:79","128:129","130:131","180:181","182:183","232:233","234:235"
#define W8  "80:81","82:83","132:133","134:135","184:185","186:187","236:237","238:239"
#define W9  "84:85","86:87","136:137","138:139","188:189","190:191","240:241","242:243"
#define W10 "88:89","90:91","140:141","142:143","192:193","194:195","244:245","246:247"
#define W11 "92:93","94:95","144:145","146:147","196:197","198:199","248:249","250:251"
#define W12 "96:97","98:99","148:149","150:151","200:201","202:203","252:253","254:255"
#define SL0 "0:1","2:3"
#define SL1 "4:5","6:7"
#define SL2 "8:9","10:11"
#define SL3 "12:13","14:15"
#define SL4 "16:17","18:19"
#define SL5 "20:21","22:23"
#define SL6 "24:25","26:27"

__global__ __attribute__((amdgpu_flat_work_group_size(64, 64),
                          amdgpu_waves_per_eu(1, 1)))
void rec_lstm_kernel(const float* __restrict__ x,
                     const float* __restrict__ W_ih,
                     const float* __restrict__ W_hh,
                     const float* __restrict__ b_ih,
                     const float* __restrict__ b_hh,
                     const float* __restrict__ W_fc,
                     const float* __restrict__ b_fc,
                     const int*   __restrict__ num_pred,
                     float*       __restrict__ out)
{
    const int b = blockIdx.x;
    const int j = threadIdx.x;

    // LDS: h_ext[64] @0 (h_ext = [1, xv, h0..h49]), xbuf[112] @256B
    __shared__ __align__(16) float lds[176];
    if (j < 48) { lds[64 + j] = x[b*TLEN + j]; lds[64 + j + 48] = x[b*TLEN + j + 48]; }

    const int NP = num_pred[0];
    const uint32_t lb = (uint32_t)(uintptr_t)&lds[0];

    asm volatile(
        // ============ once: consts, lane calc, weight load ============
        "s_load_dword s25, %[bfcp], 0x0\n\t"
        "s_waitcnt lgkmcnt(0)\n\t"
        "v_mbcnt_lo_u32_b32 v0, -1, 0\n\t"
        "v_mbcnt_hi_u32_b32 v0, -1, v0\n\t"
        "s_mov_b32 s22, 49\n\t"
        "v_min_u32 v1, s22, v0\n\t"               // u = min(lane,49)
        "s_mov_b32 s22, 200\n\t"
        "v_mul_lo_u32 v2, s22, v1\n\t"            // i-row byte off
        "s_mov_b32 s22, 10000\n\t"
        "v_add_u32 v3, s22, v2\n\t"               // f-row
        "s_mov_b32 s22, 20000\n\t"
        "v_add_u32 v4, s22, v2\n\t"               // g-row
        "s_mov_b32 s22, 30000\n\t"
        "v_add_u32 v5, s22, v2\n\t"               // o-row
        "v_lshlrev_b32 v6, 2, v1\n\t"             // u*4
        "global_load_dword v48,  v6, %[bih]\n\t"
        "global_load_dword v100, v6, %[bih] offset:200\n\t"
        "global_load_dword v152, v6, %[bih] offset:400\n\t"
        "global_load_dword v204, v6, %[bih] offset:600\n\t"
        "global_load_dword v7,  v6, %[bhh]\n\t"
        "global_load_dword v8,  v6, %[bhh] offset:200\n\t"
        "global_load_dword v9,  v6, %[bhh] offset:400\n\t"
        "global_load_dword v10, v6, %[bhh] offset:600\n\t"
        "global_load_dword v49,  v6, %[wih]\n\t"
        "global_load_dword v101, v6, %[wih] offset:200\n\t"
        "global_load_dword v153, v6, %[wih] offset:400\n\t"
        "global_load_dword v205, v6, %[wih] offset:600\n\t"
        "global_load_dword v41, v6, %[wfcp]\n\t"
        "global_load_dwordx4 v[50:53], v2, %[whh]\n\t"
        "global_load_dwordx4 v[54:57], v2, %[whh] offset:16\n\t"
        "global_load_dwordx4 v[58:61], v2, %[whh] offset:32\n\t"
        "global_load_dwordx4 v[62:65], v2, %[whh] offset:48\n\t"
        "global_load_dwordx4 v[66:69], v2, %[whh] offset:64\n\t"
        "global_load_dwordx4 v[70:73], v2, %[whh] offset:80\n\t"
        "global_load_dwordx4 v[74:77], v2, %[whh] offset:96\n\t"
        "global_load_dwordx4 v[78:81], v2, %[whh] offset:112\n\t"
        "global_load_dwordx4 v[82:85], v2, %[whh] offset:128\n\t"
        "global_load_dwordx4 v[86:89], v2, %[whh] offset:144\n\t"
        "global_load_dwordx4 v[90:93], v2, %[whh] offset:160\n\t"
        "global_load_dwordx4 v[94:97], v2, %[whh] offset:176\n\t"
        "global_load_dwordx2 v[98:99], v2, %[whh] offset:192\n\t"
        "global_load_dwordx4 v[102:105], v3, %[whh]\n\t"
        "global_load_dwordx4 v[106:109], v3, %[whh] offset:16\n\t"
        "global_load_dwordx4 v[110:113], v3, %[whh] offset:32\n\t"
        "global_load_dwordx4 v[114:117], v3, %[whh] offset:48\n\t"
        "global_load_dwordx4 v[118:121], v3, %[whh] offset:64\n\t"
        "global_load_dwordx4 v[122:125], v3, %[whh] offset:80\n\t"
        "global_load_dwordx4 v[126:129], v3, %[whh] offset:96\n\t"
        "global_load_dwordx4 v[130:133], v3, %[whh] offset:112\n\t"
        "global_load_dwordx4 v[134:137], v3, %[whh] offset:128\n\t"
        "global_load_dwordx4 v[138:141], v3, %[whh] offset:144\n\t"
        "global_load_dwordx4 v[142:145], v3, %[whh] offset:160\n\t"
        "global_load_dwordx4 v[146:149], v3, %[whh] offset:176\n\t"
        "global_load_dwordx2 v[150:151], v3, %[whh] offset:192\n\t"
        "global_load_dwordx4 v[154:157], v4, %[whh]\n\t"
        "global_load_dwordx4 v[158:161], v4, %[whh] offset:16\n\t"
        "global_load_dwordx4 v[162:165], v4, %[whh] offset:32\n\t"
        "global_load_dwordx4 v[166:169], v4, %[whh] offset:48\n\t"
        "global_load_dwordx4 v[170:173], v4, %[whh] offset:64\n\t"
        "global_load_dwordx4 v[174:177], v4, %[whh] offset:80\n\t"
        "global_load_dwordx4 v[178:181], v4, %[whh] offset:96\n\t"
        "global_load_dwordx4 v[182:185], v4, %[whh] offset:112\n\t"
        "global_load_dwordx4 v[186:189], v4, %[whh] offset:128\n\t"
        "global_load_dwordx4 v[190:193], v4, %[whh] offset:144\n\t"
        "global_load_dwordx4 v[194:197], v4, %[whh] offset:160\n\t"
        "global_load_dwordx4 v[198:201], v4, %[whh] offset:176\n\t"
        "global_load_dwordx2 v[202:203], v4, %[whh] offset:192\n\t"
        "global_load_dwordx4 v[206:209], v5, %[whh]\n\t"
        "global_load_dwordx4 v[210:213], v5, %[whh] offset:16\n\t"
        "global_load_dwordx4 v[214:217], v5, %[whh] offset:32\n\t"
        "global_load_dwordx4 v[218:221], v5, %[whh] offset:48\n\t"
        "global_load_dwordx4 v[222:225], v5, %[whh] offset:64\n\t"
        "global_load_dwordx4 v[226:229], v5, %[whh] offset:80\n\t"
        "global_load_dwordx4 v[230:233], v5, %[whh] offset:96\n\t"
        "global_load_dwordx4 v[234:237], v5, %[whh] offset:112\n\t"
        "global_load_dwordx4 v[238:241], v5, %[whh] offset:128\n\t"
        "global_load_dwordx4 v[242:245], v5, %[whh] offset:144\n\t"
        "global_load_dwordx4 v[246:249], v5, %[whh] offset:160\n\t"
        "global_load_dwordx4 v[250:253], v5, %[whh] offset:176\n\t"
        "global_load_dwordx2 v[254:255], v5, %[whh] offset:192\n\t"
        "s_waitcnt vmcnt(0)\n\t"
        "v_add_f32 v48,  v48,  v7\n\t"            // b = b_ih + b_hh
        "v_add_f32 v100, v100, v8\n\t"
        "v_add_f32 v152, v152, v9\n\t"
        "v_add_f32 v204, v204, v10\n\t"
        "v_cmp_gt_u32 vcc, 50, v0\n\t"
        "v_cndmask_b32 v41, 0, v41, vcc\n\t"      // wfc (0 for idle lanes)
        "v_mov_b32 v38, %[lb]\n\t"                // lds base
        "v_lshl_add_u32 v39, v1, 2, v38\n\t"
        "v_add_u32 v39, 8, v39\n\t"               // hn write addr h_ext[2+u]
        "v_add_u32 v40, 0x100, v38\n\t"           // xa = &xbuf[0]
        "v_mov_b32 v44, 1.0\n\t"
        "ds_write_b32 v38, v44\n\t"               // h_ext[0] = 1.0 (static)
        "s_mov_b32 s21, %[np]\n\t"
        // ===================== pass loop =====================
        "4:\n\t"
        "v_mov_b32 v36, 0\n\t"                    // c = 0
        "v_mov_b32 v44, 0\n\t"
        "ds_write_b32 v39, v44\n\t"               // h[2+u] = 0
        "ds_read_b32 v42, v40\n\t"                // x(p+0)
        "s_waitcnt lgkmcnt(0)\n\t"
        "ds_write_b32 v38, v42 offset:4\n\t"      // h_ext[1] = xv(t=0)
        "ds_read_b128 v[0:3],   v38 offset:0\n\t"   // R1..R7
        "ds_read_b128 v[4:7],   v38 offset:16\n\t"
        "ds_read_b128 v[8:11],  v38 offset:32\n\t"
        "ds_read_b128 v[12:15], v38 offset:48\n\t"
        "ds_read_b128 v[16:19], v38 offset:64\n\t"
        "ds_read_b128 v[20:23], v38 offset:80\n\t"
        "ds_read_b128 v[24:27], v38 offset:96\n\t"
        "s_mov_b32 s20, 96\n\t"
        // ===================== step loop =====================
        "3:\n\t"
        "ds_read_b32 v42, v40 offset:4\n\t"       // xv(t+1)
        GRPMX("7", ACC, W0,  SL0, "ds_read_b128 v[0:3],   v38 offset:112\n\t")
        GRPX("7",  ACC, W1,  SL1, "ds_read_b128 v[4:7],   v38 offset:128\n\t")
        GRPX("7",  ACC, W2,  SL2, "ds_read_b128 v[8:11],  v38 offset:144\n\t")
        GRPX("7",  ACC, W3,  SL3, "ds_read_b128 v[12:15], v38 offset:160\n\t")
        GRPX("7",  ACC, W4,  SL4, "ds_read_b128 v[16:19], v38 offset:176\n\t")
        GRPX("7",  ACC, W5,  SL5, "ds_read_b128 v[20:23], v38 offset:192\n\t")
        GRPX("7",  ACC, W6,  SL6, "")
        GRPX("5",  ACC, W7,  SL0, "")
        GRPX("4",  ACC, W8,  SL1, "")
        GRPX("3",  ACC, W9,  SL2, "")
        GRPX("2",  ACC, W10, SL3, "")
        GRPX("1",  ACC, W11, SL4, "")
        GRPX("0",  ACC, W12, SL5, "")
        // ---- fold + tail ----
        "v_add_f32 v28, v28, v29\n\t"
        "v_add_f32 v30, v30, v31\n\t"
        "v_add_f32 v32, v32, v33\n\t"
        "v_add_f32 v34, v34, v35\n\t"
        "v_mul_f32 v29, 0xbfb8aa3b, v28\n\t"
        "v_mul_f32 v31, 0xbfb8aa3b, v30\n\t"
        "v_mul_f32 v33, 0x4038aa3b, v32\n\t"
        "v_mul_f32 v35, 0xbfb8aa3b, v34\n\t"
        "v_exp_f32 v29, v29\n\t"
        "v_exp_f32 v31, v31\n\t"
        "v_exp_f32 v33, v33\n\t"
        "v_exp_f32 v35, v35\n\t"
        "v_add_f32 v29, 1.0, v29\n\t"
        "v_add_f32 v31, 1.0, v31\n\t"
        "v_add_f32 v33, 1.0, v33\n\t"
        "v_add_f32 v35, 1.0, v35\n\t"
        "v_rcp_f32 v29, v29\n\t"
        "v_rcp_f32 v31, v31\n\t"
        "v_rcp_f32 v33, v33\n\t"
        "v_rcp_f32 v35, v35\n\t"
        "s_nop 1\n\t"
        "v_fma_f32 v33, -2.0, v33, 1.0\n\t"       // tanh(g)
        "v_mul_f32 v29, v29, v33\n\t"             // i*g
        "v_fma_f32 v36, v31, v36, v29\n\t"        // c = f*c + i*g
        "v_mul_f32 v31, 0x4038aa3b, v36\n\t"
        "v_exp_f32 v31, v31\n\t"
        "s_nop 1\n\t"
        "v_add_f32 v31, 1.0, v31\n\t"
        "v_rcp_f32 v31, v31\n\t"
        "s_nop 1\n\t"
        "v_fma_f32 v31, -2.0, v31, 1.0\n\t"       // tanh(c)
        "v_mul_f32 v37, v35, v31\n\t"             // hn = o * tanh(c)
        // ---- hn + x(t+1) writes, then next step's 7 reads immediately ----
        "ds_write_b32 v39, v37\n\t"
        "ds_write_b32 v38, v42 offset:4\n\t"
        "ds_read_b128 v[0:3],   v38 offset:0\n\t"
        "ds_read_b128 v[4:7],   v38 offset:16\n\t"
        "ds_read_b128 v[8:11],  v38 offset:32\n\t"
        "ds_read_b128 v[12:15], v38 offset:48\n\t"
        "ds_read_b128 v[16:19], v38 offset:64\n\t"
        "ds_read_b128 v[20:23], v38 offset:80\n\t"
        "ds_read_b128 v[24:27], v38 offset:96\n\t"
        "v_add_u32 v40, 4, v40\n\t"
        "s_sub_u32 s20, s20, 1\n\t"
        "s_cmp_lg_u32 s20, 0\n\t"
        "s_cbranch_scc1 3b\n\t"
        // ===================== FC head =====================
        "v_mul_f32 v44, v37, v41\n\t"
        "s_nop 1\n\t"
        "ds_swizzle_b32 v45, v44 offset:0x041F\n\t"
        "s_waitcnt lgkmcnt(0)\n\t"
        "v_add_f32 v44, v44, v45\n\t"
        "ds_swizzle_b32 v45, v44 offset:0x081F\n\t"
        "s_waitcnt lgkmcnt(0)\n\t"
        "v_add_f32 v44, v44, v45\n\t"
        "ds_swizzle_b32 v45, v44 offset:0x101F\n\t"
        "s_waitcnt lgkmcnt(0)\n\t"
        "v_add_f32 v44, v44, v45\n\t"
        "ds_swizzle_b32 v45, v44 offset:0x201F\n\t"
        "s_waitcnt lgkmcnt(0)\n\t"
        "v_add_f32 v44, v44, v45\n\t"
        "ds_swizzle_b32 v45, v44 offset:0x401F\n\t"
        "s_waitcnt lgkmcnt(0)\n\t"
        "v_add_f32 v44, v44, v45\n\t"
        "s_nop 1\n\t"
        "v_readlane_b32 s26, v44, 0\n\t"
        "v_readlane_b32 s27, v44, 32\n\t"
        "s_nop 4\n\t"
        "v_mov_b32 v45, s26\n\t"
        "v_add_f32 v45, s27, v45\n\t"
        "v_add_f32 v45, s25, v45\n\t"
        "ds_write_b32 v40, v45\n\t"               // pred -> xbuf[96+p] (== xa)
        "s_waitcnt lgkmcnt(0)\n\t"
        "v_add_u32 v40, 0xfffffe84, v40\n\t"      // xa -> &xbuf[p+1]  (-380)
        "s_sub_u32 s21, s21, 1\n\t"
        "s_cmp_lg_u32 s21, 0\n\t"
        "s_cbranch_scc1 4b\n\t"
        :
        : [lb] "v"(lb), [np] "s"(NP),
          [whh] "s"(W_hh), [wih] "s"(W_ih), [bih] "s"(b_ih), [bhh] "s"(b_hh),
          [wfcp] "s"(W_fc), [bfcp] "s"(b_fc)
        : "memory", "scc", "vcc", "s20", "s21", "s22", "s25", "s26", "s27",
          "v0","v1","v2","v3","v4","v5","v6","v7","v8","v9","v10","v11",
          "v12","v13","v14","v15","v16","v17","v18","v19","v20","v21","v22",
          "v23","v24","v25","v26","v27","v28","v29","v30","v31","v32","v33",
          "v34","v35","v36","v37","v38","v39","v40","v41","v42","v43","v44",
          "v45",
          "v48","v49","v50","v51","v52","v53","v54","v55","v56","v57","v58",
          "v59","v60","v61","v62","v63","v64","v65","v66","v67","v68","v69",
          "v70","v71","v72","v73","v74","v75","v76","v77","v78","v79","v80",
          "v81","v82","v83","v84","v85","v86","v87","v88","v89","v90","v91",
          "v92","v93","v94","v95","v96","v97","v98","v99","v100","v101",
          "v102","v103","v104","v105","v106","v107","v108","v109","v110",
          "v111","v112","v113","v114","v115","v116","v117","v118","v119",
          "v120","v121","v122","v123","v124","v125","v126","v127","v128",
          "v129","v130","v131","v132","v133","v134","v135","v136","v137",
          "v138","v139","v140","v141","v142","v143","v144","v145","v146",
          "v147","v148","v149","v150","v151","v152","v153","v154","v155",
          "v156","v157","v158","v159","v160","v161","v162","v163","v164",
          "v165","v166","v167","v168","v169","v170","v171","v172","v173",
          "v174","v175","v176","v177","v178","v179","v180","v181","v182",
          "v183","v184","v185","v186","v187","v188","v189","v190","v191",
          "v192","v193","v194","v195","v196","v197","v198","v199","v200",
          "v201","v202","v203","v204","v205","v206","v207","v208","v209",
          "v210","v211","v212","v213","v214","v215","v216","v217","v218",
          "v219","v220","v221","v222","v223","v224","v225","v226","v227",
          "v228","v229","v230","v231","v232","v233","v234","v235","v236",
          "v237","v238","v239","v240","v241","v242","v243","v244","v245",
          "v246","v247","v248","v249","v250","v251","v252","v253","v254",
          "v255");

    if (j < NP) out[b * NP + j] = lds[64 + TLEN + j];
}

extern "C" void kernel_launch(void* const* d_in, const int* in_sizes, int n_in,
                              void* d_out, int out_size, void* d_ws, size_t ws_size,
                              hipStream_t stream)
{
    const float* x    = (const float*)d_in[0];
    const float* W_ih = (const float*)d_in[1];
    const float* W_hh = (const float*)d_in[2];
    const float* b_ih = (const float*)d_in[3];
    const float* b_hh = (const float*)d_in[4];
    const float* W_fc = (const float*)d_in[5];
    const float* b_fc = (const float*)d_in[6];
    const int*   np   = (const int*)d_in[7];
    float* out = (float*)d_out;

    const int B = in_sizes[0] / TLEN;   // 1024
    rec_lstm_kernel<<<B, 64, 0, stream>>>(x, W_ih, W_hh, b_ih, b_hh,
                                          W_fc, b_fc, np, out);
}